// Round 7
// baseline (202.399 us; speedup 1.0000x reference)
//
#include <hip/hip_runtime.h>
#include <hip/hip_fp16.h>

namespace {

constexpr int B = 128, N = 2048, E = 32768;
constexpr int LOG2N = 11, LOG2E = 15;
constexpr int DMAX = 128;  // ELL rows per batch (Poisson(16) max ~45; clamped for safety)

// ws layout (bytes)
constexpr size_t OFF_H0  = 0;                      // B*N float4 = 4 MB   (rank-ordered)
constexpr size_t OFF_H1  = 4u * 1024 * 1024;       // B*N float4 = 4 MB   (rank-ordered)
constexpr size_t OFF_ELL = 8u * 1024 * 1024;       // B*DMAX*N u32 = 128 MB
constexpr size_t OFF_NR  = 136u * 1024 * 1024;     // B*N u32: rank -> node|(deg<<16)
constexpr size_t OFF_INV = 138u * 1024 * 1024;     // B*N int: node -> rank

// One block per batch: LDS counting-sort of edges by dst into a packed CSR
// (src | f16(dt)<<16), then counting-sort NODES by degree and transpose the
// CSR into rank-major ELL:  ell[b][j][r] = j-th record of rank-r node.
// Rank-major ELL gives the layer kernel (a) coalesced record loads
// (consecutive lanes = consecutive ranks = consecutive 4B) and (b) near-zero
// wave divergence (a wave's 64 ranks have ~equal degree).
// All randomness stays in LDS; global IO is streaming (R2/R4: random global
// writes cost ~60B/access; R5: LDS atomics are the other tax — 2/edge here).
__global__ __launch_bounds__(1024) void sort_kernel(const int* __restrict__ edge_index,
                                                    const float* __restrict__ edge_time,
                                                    const float* __restrict__ timestamp,
                                                    unsigned* __restrict__ ell,
                                                    unsigned* __restrict__ nr_out,
                                                    int* __restrict__ inv_out) {
  __shared__ int      cnt[N];       // 8 KB  counts -> cursors
  __shared__ int      rbase[N];     // 8 KB  segment starts
  __shared__ int      partial[1024];// 4 KB
  __shared__ unsigned nrp[N];       // 8 KB  rank -> node|(deg<<16)
  __shared__ int      dhist[64];    // 256 B degree buckets
  __shared__ unsigned rec[E];       // 128 KB packed CSR    => 156.5 KB total
  int b = blockIdx.x, t = threadIdx.x;
  const int* src_arr = edge_index + ((size_t)(2 * b) << LOG2E);
  const int* dst_arr = src_arr + E;
  const float* et    = edge_time + ((size_t)b << LOG2E);
  float ts = timestamp[b];

  cnt[t] = 0; cnt[t + 1024] = 0;
  if (t < 64) dhist[t] = 0;
  __syncthreads();

  for (int e = t; e < E; e += 1024) atomicAdd(&cnt[dst_arr[e]], 1);
  __syncthreads();

  // exclusive scan of 2048 counts (2/thread)
  int i0 = 2 * t, i1 = 2 * t + 1;
  int l0 = cnt[i0], l1 = cnt[i1], sum = l0 + l1;
  partial[t] = sum;
  __syncthreads();
  for (int d = 1; d < 1024; d <<= 1) {
    int v = (t >= d) ? partial[t - d] : 0;
    __syncthreads();
    partial[t] += v;
    __syncthreads();
  }
  int run = partial[t] - sum;
  rbase[i0] = run;      rbase[i1] = run + l0;
  cnt[i0]   = run;      cnt[i1]   = run + l0;   // cursors
  __syncthreads();

  // scatter packed records into LDS CSR
  for (int e = t; e < E; e += 1024) {
    int dst = dst_arr[e], src = src_arr[e];
    float dt = ts - et[e];
    unsigned hd = (unsigned)__half_as_ushort(__float2half(dt));
    int pos = atomicAdd(&cnt[dst], 1);
    rec[pos] = (unsigned)src | (hd << 16);
  }
  __syncthreads();

  // degree histogram (bucket = min(deg,63))
  for (int n = t; n < N; n += 1024) {
    int deg = cnt[n] - rbase[n];
    atomicAdd(&dhist[min(deg, 63)], 1);
  }
  __syncthreads();
  if (t == 0) {
    int acc = 0;
    for (int k = 0; k < 64; k++) { int c = dhist[k]; dhist[k] = acc; acc += c; }
  }
  __syncthreads();

  // rank assignment (counting sort by degree; order within bucket arbitrary)
  for (int n = t; n < N; n += 1024) {
    int deg = cnt[n] - rbase[n];
    int r = atomicAdd(&dhist[min(deg, 63)], 1);
    nrp[r] = (unsigned)n | ((unsigned)deg << 16);
    inv_out[((size_t)b << LOG2N) + n] = r;
  }
  __syncthreads();

  nr_out[((size_t)b << LOG2N) + t] = nrp[t];
  nr_out[((size_t)b << LOG2N) + t + 1024] = nrp[t + 1024];

  // transpose CSR -> rank-major ELL (writes coalesced: consecutive lanes r)
  size_t ebase = (size_t)b * DMAX * N;
  for (int r = t; r < N; r += 1024) {
    unsigned pk = nrp[r];
    int n = pk & 0xFFFF;
    int deg = min((int)(pk >> 16), DMAX);
    int base = rbase[n];
    for (int j = 0; j < deg; j++)
      ell[ebase + ((size_t)j << LOG2N) + r] = rec[base + j];
  }
}

// 2 blocks per batch, thread t <-> rank r. ELL record loads coalesced,
// wave divergence ~none (ranks sorted by degree). h buffers rank-ordered.
__global__ __launch_bounds__(1024) void layer_kernel(const float4* __restrict__ h_in,
                                                     int in_ranked,
                                                     float4* __restrict__ h_out,
                                                     const unsigned* __restrict__ nr_g,
                                                     const unsigned* __restrict__ ell,
                                                     const float* __restrict__ tw,
                                                     const float* __restrict__ tb,
                                                     const float* __restrict__ Wq,
                                                     const float* __restrict__ Wk,
                                                     const float* __restrict__ Wv,
                                                     const float* __restrict__ Wo,
                                                     const float* __restrict__ bo) {
  __shared__ float4   lh[N];    // 32 KB, node-indexed
  __shared__ unsigned lnr[N];   // 8 KB, rank -> node|(deg<<16)
  int blk = blockIdx.x, b = blk >> 1, rh = blk & 1, t = threadIdx.x;

  unsigned pk0 = nr_g[((size_t)b << LOG2N) + t];
  unsigned pk1 = nr_g[((size_t)b << LOG2N) + t + 1024];
  lnr[t] = pk0; lnr[t + 1024] = pk1;
  const float4* hb = h_in + ((size_t)b << LOG2N);
  float4 s0v = hb[t], s1v = hb[t + 1024];
  if (in_ranked) {  // un-permute rank-ordered h into node-indexed LDS
    lh[pk0 & 0xFFFF] = s0v;
    lh[pk1 & 0xFFFF] = s1v;
  } else {          // layer 0: x is node-ordered already
    lh[t] = s0v;
    lh[t + 1024] = s1v;
  }

  float twf[4], tbf[4], bof[4], wq[16], wof[16], wk[32], wv[32];
#pragma unroll
  for (int j = 0; j < 4; j++) { twf[j] = tw[j]; tbf[j] = tb[j]; bof[j] = bo[j]; }
#pragma unroll
  for (int j = 0; j < 16; j++) { wq[j] = Wq[j]; wof[j] = Wo[j]; }
#pragma unroll
  for (int j = 0; j < 32; j++) { wk[j] = Wk[j]; wv[j] = Wv[j]; }
  __syncthreads();

  int r = (rh << 10) + t;
  unsigned pk = lnr[r];
  int n = pk & 0xFFFF;
  int deg = min((int)(pk >> 16), DMAX);
  float4 hn = lh[n];
  float q0 = hn.x * wq[0] + hn.y * wq[4] + hn.z * wq[8]  + hn.w * wq[12];
  float q1 = hn.x * wq[1] + hn.y * wq[5] + hn.z * wq[9]  + hn.w * wq[13];
  float q2 = hn.x * wq[2] + hn.y * wq[6] + hn.z * wq[10] + hn.w * wq[14];
  float q3 = hn.x * wq[3] + hn.y * wq[7] + hn.z * wq[11] + hn.w * wq[15];
  const float RS2 = 0.70710678118654752f;
  float u0[8], u1[8];
#pragma unroll
  for (int j = 0; j < 8; j++) {
    u0[j] = RS2 * (q0 * wk[j * 4 + 0] + q1 * wk[j * 4 + 1]);
    u1[j] = RS2 * (q2 * wk[j * 4 + 2] + q3 * wk[j * 4 + 3]);
  }

  float m0 = -INFINITY, m1 = -INFINITY;
  float s0 = 0.f, s1 = 0.f, a00 = 0.f, a01 = 0.f, a10 = 0.f, a11 = 0.f;
  const unsigned* eb = ell + (size_t)b * DMAX * N + r;

  unsigned rc = (deg > 0) ? eb[0] : 0u;  // 1-deep prefetch hides L2 latency
  for (int j = 0; j < deg; ++j) {
    unsigned rc_next = (j + 1 < deg) ? eb[(size_t)(j + 1) << LOG2N] : 0u;
    int src = rc & 0xFFFF;
    float dt = __half2float(__ushort_as_half((unsigned short)(rc >> 16)));
    float4 hs = lh[src];
    float p0c = __cosf(dt * twf[0] + tbf[0]);
    float p1c = __cosf(dt * twf[1] + tbf[1]);
    float p2c = __cosf(dt * twf[2] + tbf[2]);
    float p3c = __cosf(dt * twf[3] + tbf[3]);
    float l0 = u0[0] * hs.x + u0[1] * hs.y + u0[2] * hs.z + u0[3] * hs.w
             + u0[4] * p0c + u0[5] * p1c + u0[6] * p2c + u0[7] * p3c;
    float l1 = u1[0] * hs.x + u1[1] * hs.y + u1[2] * hs.z + u1[3] * hs.w
             + u1[4] * p0c + u1[5] * p1c + u1[6] * p2c + u1[7] * p3c;
    float v0 = wv[0] * hs.x + wv[4] * hs.y + wv[8]  * hs.z + wv[12] * hs.w
             + wv[16] * p0c + wv[20] * p1c + wv[24] * p2c + wv[28] * p3c;
    float v1 = wv[1] * hs.x + wv[5] * hs.y + wv[9]  * hs.z + wv[13] * hs.w
             + wv[17] * p0c + wv[21] * p1c + wv[25] * p2c + wv[29] * p3c;
    float v2 = wv[2] * hs.x + wv[6] * hs.y + wv[10] * hs.z + wv[14] * hs.w
             + wv[18] * p0c + wv[22] * p1c + wv[26] * p2c + wv[30] * p3c;
    float v3 = wv[3] * hs.x + wv[7] * hs.y + wv[11] * hs.z + wv[15] * hs.w
             + wv[19] * p0c + wv[23] * p1c + wv[27] * p2c + wv[31] * p3c;
    float nm0 = fmaxf(m0, l0);
    float sc0 = __expf(m0 - nm0);
    float p0  = __expf(l0 - nm0);
    s0 = s0 * sc0 + p0; a00 = a00 * sc0 + p0 * v0; a01 = a01 * sc0 + p0 * v1; m0 = nm0;
    float nm1 = fmaxf(m1, l1);
    float sc1 = __expf(m1 - nm1);
    float p1  = __expf(l1 - nm1);
    s1 = s1 * sc1 + p1; a10 = a10 * sc1 + p1 * v2; a11 = a11 * sc1 + p1 * v3; m1 = nm1;
    rc = rc_next;
  }
  float d0 = (s0 == 0.f) ? 1.f : s0;
  float d1 = (s1 == 0.f) ? 1.f : s1;
  float at0 = a00 / d0, at1 = a01 / d0, at2 = a10 / d1, at3 = a11 / d1;
  float o0 = bof[0] + at0 * wof[0] + at1 * wof[4] + at2 * wof[8]  + at3 * wof[12];
  float o1 = bof[1] + at0 * wof[1] + at1 * wof[5] + at2 * wof[9]  + at3 * wof[13];
  float o2 = bof[2] + at0 * wof[2] + at1 * wof[6] + at2 * wof[10] + at3 * wof[14];
  float o3 = bof[3] + at0 * wof[3] + at1 * wof[7] + at2 * wof[11] + at3 * wof[15];
  // rank-ordered output: coalesced
  h_out[((size_t)b << LOG2N) + r] =
      make_float4(fmaxf(hn.x + o0, 0.f), fmaxf(hn.y + o1, 0.f),
                  fmaxf(hn.z + o2, 0.f), fmaxf(hn.w + o3, 0.f));
}

__global__ void final_kernel(const float4* __restrict__ h,   // rank-ordered
                             const int* __restrict__ inv,    // node -> rank
                             const int* __restrict__ src_index, const int* __restrict__ dst_index,
                             const float* __restrict__ timestamp,
                             const float* __restrict__ tw,
                             const float* __restrict__ tb,
                             const float* __restrict__ W_lin,
                             const float* __restrict__ b_lin,
                             float* __restrict__ out) {
  int b = threadIdx.x;
  if (b >= B) return;
  int rs = inv[((size_t)b << LOG2N) + src_index[b]];
  int rd = inv[((size_t)b << LOG2N) + dst_index[b]];
  float4 sx = h[((size_t)b << LOG2N) + rs];
  float4 dx = h[((size_t)b << LOG2N) + rd];
  float ts = timestamp[b];
  float f[12];
  f[0] = sx.x; f[1] = sx.y; f[2] = sx.z; f[3] = sx.w;
  f[4] = dx.x; f[5] = dx.y; f[6] = dx.z; f[7] = dx.w;
#pragma unroll
  for (int j = 0; j < 4; j++) f[8 + j] = __cosf(ts * tw[j] + tb[j]);
#pragma unroll
  for (int c = 0; c < 2; c++) {
    float o = b_lin[c];
#pragma unroll
    for (int j = 0; j < 12; j++) o += f[j] * W_lin[j * 2 + c];
    out[b * 2 + c] = o;
  }
}

}  // namespace

extern "C" void kernel_launch(void* const* d_in, const int* in_sizes, int n_in,
                              void* d_out, int out_size, void* d_ws, size_t ws_size,
                              hipStream_t stream) {
  (void)in_sizes; (void)n_in; (void)out_size; (void)ws_size;
  const float* x         = (const float*)d_in[0];
  const int*   edge_idx  = (const int*)d_in[1];
  const float* edge_time = (const float*)d_in[2];
  const float* timestamp = (const float*)d_in[3];
  const int*   src_index = (const int*)d_in[4];
  const int*   dst_index = (const int*)d_in[5];
  const float* time_w    = (const float*)d_in[6];
  const float* time_b    = (const float*)d_in[7];
  const float* Wq        = (const float*)d_in[8];
  const float* Wk        = (const float*)d_in[9];
  const float* Wv        = (const float*)d_in[10];
  const float* Wo        = (const float*)d_in[11];
  const float* bo        = (const float*)d_in[12];
  const float* W_lin     = (const float*)d_in[13];
  const float* b_lin     = (const float*)d_in[14];

  char* ws = (char*)d_ws;
  float4*   h0  = (float4*)(ws + OFF_H0);
  float4*   h1  = (float4*)(ws + OFF_H1);
  unsigned* ell = (unsigned*)(ws + OFF_ELL);
  unsigned* nr  = (unsigned*)(ws + OFF_NR);
  int*      inv = (int*)(ws + OFF_INV);

  sort_kernel<<<B, 1024, 0, stream>>>(edge_idx, edge_time, timestamp, ell, nr, inv);

  layer_kernel<<<2 * B, 1024, 0, stream>>>((const float4*)x, 0, h1, nr, ell,
                                           time_w, time_b,
                                           Wq + 0 * 16, Wk + 0 * 32, Wv + 0 * 32,
                                           Wo + 0 * 16, bo + 0 * 4);
  layer_kernel<<<2 * B, 1024, 0, stream>>>(h1, 1, h0, nr, ell,
                                           time_w, time_b,
                                           Wq + 1 * 16, Wk + 1 * 32, Wv + 1 * 32,
                                           Wo + 1 * 16, bo + 1 * 4);

  final_kernel<<<1, 128, 0, stream>>>(h0, inv, src_index, dst_index, timestamp,
                                      time_w, time_b, W_lin, b_lin, (float*)d_out);
}

// Round 8
// 201.498 us; speedup vs baseline: 1.0045x; 1.0045x over previous
//
#include <hip/hip_runtime.h>
#include <hip/hip_fp16.h>

namespace {

constexpr int B = 128, N = 2048, E = 32768;
constexpr int LOG2N = 11, LOG2E = 15;
constexpr int DMAX = 64;        // per-node ELL capacity (Binomial λ=16; P(deg>63)≈0)
constexpr int RECCAP = 17408;   // per-range record cap (mean 16384, +11σ slack)

// ws layout (bytes)
constexpr size_t OFF_H0  = 0;                      // B*N float4 = 4 MB (rank-ordered)
constexpr size_t OFF_H1  = 4u * 1024 * 1024;       // B*N float4 = 4 MB (rank-ordered)
constexpr size_t OFF_ELL = 8u * 1024 * 1024;       // B*2*DMAX*1024 u32 = 64 MB
constexpr size_t OFF_NR  = 72u * 1024 * 1024;      // B*N u32: [range][rank] -> node|(deg<<16)
constexpr size_t OFF_INV = 74u * 1024 * 1024;      // B*N int: node -> global rank

// Block (b, hr) owns dst range [hr*1024, hr*1024+1024): hist -> scan -> local
// degree-ranks -> LDS CSR -> rank-major ELL (1024 columns). Full chip (256
// blocks, ~86 KB LDS) vs R7's 128-block/160KB monolith (half chip, 47.9us).
// R2/R4: random global writes cost ~60B/access; R5: LDS atomics tax — kept
// to 2/edge here; all global IO streaming/coalesced.
__global__ __launch_bounds__(1024) void sort_kernel(const int* __restrict__ edge_index,
                                                    const float* __restrict__ edge_time,
                                                    const float* __restrict__ timestamp,
                                                    unsigned* __restrict__ ell,
                                                    unsigned* __restrict__ nr_out,
                                                    int* __restrict__ inv_out) {
  __shared__ int      cnt[1024];     // 4 KB counts -> cursors
  __shared__ int      rbase[1024];   // 4 KB segment starts
  __shared__ int      partial[1024]; // 4 KB
  __shared__ unsigned nrp[1024];     // 4 KB rank -> node|(deg<<16)
  __shared__ int      dhist[64];
  __shared__ unsigned rec[RECCAP];   // 68 KB packed CSR  => ~86 KB total
  int blk = blockIdx.x, b = blk >> 1, hr = blk & 1, t = threadIdx.x;
  int lo = hr << 10;
  const int* src_arr = edge_index + ((size_t)(2 * b) << LOG2E);
  const int* dst_arr = src_arr + E;
  const float* et    = edge_time + ((size_t)b << LOG2E);
  float ts = timestamp[b];

  cnt[t] = 0;
  if (t < 64) dhist[t] = 0;
  __syncthreads();

  // hist over in-range dsts
  for (int e = t; e < E; e += 1024) {
    int d = dst_arr[e];
    if ((d >> 10) == hr) atomicAdd(&cnt[d & 1023], 1);
  }
  __syncthreads();

  // exclusive scan, 1 element/thread
  int c = cnt[t];
  partial[t] = c;
  __syncthreads();
  for (int d = 1; d < 1024; d <<= 1) {
    int v = (t >= d) ? partial[t - d] : 0;
    __syncthreads();
    partial[t] += v;
    __syncthreads();
  }
  int run = partial[t] - c;
  rbase[t] = run;
  cnt[t] = run;  // cursor
  int deg = c;
  atomicAdd(&dhist[min(deg, 63)], 1);
  __syncthreads();
  if (t == 0) {
    int acc = 0;
    for (int k = 0; k < 64; k++) { int cc = dhist[k]; dhist[k] = acc; acc += cc; }
  }
  __syncthreads();
  int r = atomicAdd(&dhist[min(deg, 63)], 1);      // local rank, degree-sorted
  nrp[r] = (unsigned)(lo + t) | ((unsigned)deg << 16);
  inv_out[((size_t)b << LOG2N) + lo + t] = lo + r;  // global rank
  __syncthreads();
  nr_out[((size_t)b << LOG2N) + lo + t] = nrp[t];

  // scatter packed (src | f16(dt)<<16) into LDS CSR
  for (int e = t; e < E; e += 1024) {
    int d = dst_arr[e];
    if ((d >> 10) == hr) {
      int src = src_arr[e];
      float dt = ts - et[e];
      unsigned hd = (unsigned)__half_as_ushort(__float2half(dt));
      int pos = atomicAdd(&cnt[d & 1023], 1);
      rec[pos] = (unsigned)src | (hd << 16);
    }
  }
  __syncthreads();

  // transpose -> rank-major ELL; thread t = rank t (degree-uniform waves,
  // coalesced writes: consecutive t -> consecutive 4B)
  unsigned pk = nrp[t];
  int nloc = (int)(pk & 1023u);
  int dg = min((int)(pk >> 16), DMAX);
  int base = rbase[nloc];
  size_t ebase = (size_t)blk * DMAX * 1024;
  for (int j = 0; j < dg; j++)
    ell[ebase + ((size_t)j << 10) + t] = rec[base + j];
}

// 2 blocks per batch; block rh walks its range's ELL, thread t <-> rank t.
// Coalesced record loads, near-zero wave divergence. h buffers rank-ordered.
__global__ __launch_bounds__(1024) void layer_kernel(const float4* __restrict__ h_in,
                                                     int in_ranked,
                                                     float4* __restrict__ h_out,
                                                     const unsigned* __restrict__ nr_g,
                                                     const unsigned* __restrict__ ell,
                                                     const float* __restrict__ tw,
                                                     const float* __restrict__ tb,
                                                     const float* __restrict__ Wq,
                                                     const float* __restrict__ Wk,
                                                     const float* __restrict__ Wv,
                                                     const float* __restrict__ Wo,
                                                     const float* __restrict__ bo) {
  __shared__ float4   lh[N];    // 32 KB, node-indexed
  __shared__ unsigned lnr[N];   // 8 KB, [range][rank] -> node|(deg<<16)
  int blk = blockIdx.x, b = blk >> 1, rh = blk & 1, t = threadIdx.x;

  unsigned pk0 = nr_g[((size_t)b << LOG2N) + t];
  unsigned pk1 = nr_g[((size_t)b << LOG2N) + t + 1024];
  lnr[t] = pk0; lnr[t + 1024] = pk1;
  const float4* hb = h_in + ((size_t)b << LOG2N);
  float4 s0v = hb[t], s1v = hb[t + 1024];
  if (in_ranked) {  // h_in[g] belongs to node lnr[g]&0xFFFF
    lh[pk0 & 0xFFFFu] = s0v;
    lh[pk1 & 0xFFFFu] = s1v;
  } else {          // layer 0: x is node-ordered
    lh[t] = s0v;
    lh[t + 1024] = s1v;
  }

  float twf[4], tbf[4], bof[4], wq[16], wof[16], wk[32], wv[32];
#pragma unroll
  for (int j = 0; j < 4; j++) { twf[j] = tw[j]; tbf[j] = tb[j]; bof[j] = bo[j]; }
#pragma unroll
  for (int j = 0; j < 16; j++) { wq[j] = Wq[j]; wof[j] = Wo[j]; }
#pragma unroll
  for (int j = 0; j < 32; j++) { wk[j] = Wk[j]; wv[j] = Wv[j]; }
  __syncthreads();

  unsigned pk = lnr[(rh << 10) + t];
  int n = (int)(pk & 0xFFFFu);
  int deg = min((int)(pk >> 16), DMAX);
  float4 hn = lh[n];
  float q0 = hn.x * wq[0] + hn.y * wq[4] + hn.z * wq[8]  + hn.w * wq[12];
  float q1 = hn.x * wq[1] + hn.y * wq[5] + hn.z * wq[9]  + hn.w * wq[13];
  float q2 = hn.x * wq[2] + hn.y * wq[6] + hn.z * wq[10] + hn.w * wq[14];
  float q3 = hn.x * wq[3] + hn.y * wq[7] + hn.z * wq[11] + hn.w * wq[15];
  const float RS2 = 0.70710678118654752f;
  float u0[8], u1[8];
#pragma unroll
  for (int j = 0; j < 8; j++) {
    u0[j] = RS2 * (q0 * wk[j * 4 + 0] + q1 * wk[j * 4 + 1]);
    u1[j] = RS2 * (q2 * wk[j * 4 + 2] + q3 * wk[j * 4 + 3]);
  }

  float m0 = -INFINITY, m1 = -INFINITY;
  float s0 = 0.f, s1 = 0.f, a00 = 0.f, a01 = 0.f, a10 = 0.f, a11 = 0.f;
  const unsigned* eb = ell + (size_t)blk * DMAX * 1024 + t;

  unsigned rc = (deg > 0) ? eb[0] : 0u;  // 1-deep prefetch
  for (int j = 0; j < deg; ++j) {
    unsigned rc_next = (j + 1 < deg) ? eb[(size_t)(j + 1) << 10] : 0u;
    int src = (int)(rc & 0xFFFFu);
    float dt = __half2float(__ushort_as_half((unsigned short)(rc >> 16)));
    float4 hs = lh[src];
    float p0c = __cosf(dt * twf[0] + tbf[0]);
    float p1c = __cosf(dt * twf[1] + tbf[1]);
    float p2c = __cosf(dt * twf[2] + tbf[2]);
    float p3c = __cosf(dt * twf[3] + tbf[3]);
    float l0 = u0[0] * hs.x + u0[1] * hs.y + u0[2] * hs.z + u0[3] * hs.w
             + u0[4] * p0c + u0[5] * p1c + u0[6] * p2c + u0[7] * p3c;
    float l1 = u1[0] * hs.x + u1[1] * hs.y + u1[2] * hs.z + u1[3] * hs.w
             + u1[4] * p0c + u1[5] * p1c + u1[6] * p2c + u1[7] * p3c;
    float v0 = wv[0] * hs.x + wv[4] * hs.y + wv[8]  * hs.z + wv[12] * hs.w
             + wv[16] * p0c + wv[20] * p1c + wv[24] * p2c + wv[28] * p3c;
    float v1 = wv[1] * hs.x + wv[5] * hs.y + wv[9]  * hs.z + wv[13] * hs.w
             + wv[17] * p0c + wv[21] * p1c + wv[25] * p2c + wv[29] * p3c;
    float v2 = wv[2] * hs.x + wv[6] * hs.y + wv[10] * hs.z + wv[14] * hs.w
             + wv[18] * p0c + wv[22] * p1c + wv[26] * p2c + wv[30] * p3c;
    float v3 = wv[3] * hs.x + wv[7] * hs.y + wv[11] * hs.z + wv[15] * hs.w
             + wv[19] * p0c + wv[23] * p1c + wv[27] * p2c + wv[31] * p3c;
    float nm0 = fmaxf(m0, l0);
    float sc0 = __expf(m0 - nm0);
    float p0  = __expf(l0 - nm0);
    s0 = s0 * sc0 + p0; a00 = a00 * sc0 + p0 * v0; a01 = a01 * sc0 + p0 * v1; m0 = nm0;
    float nm1 = fmaxf(m1, l1);
    float sc1 = __expf(m1 - nm1);
    float p1  = __expf(l1 - nm1);
    s1 = s1 * sc1 + p1; a10 = a10 * sc1 + p1 * v2; a11 = a11 * sc1 + p1 * v3; m1 = nm1;
    rc = rc_next;
  }
  float d0 = (s0 == 0.f) ? 1.f : s0;
  float d1 = (s1 == 0.f) ? 1.f : s1;
  float at0 = a00 / d0, at1 = a01 / d0, at2 = a10 / d1, at3 = a11 / d1;
  float o0 = bof[0] + at0 * wof[0] + at1 * wof[4] + at2 * wof[8]  + at3 * wof[12];
  float o1 = bof[1] + at0 * wof[1] + at1 * wof[5] + at2 * wof[9]  + at3 * wof[13];
  float o2 = bof[2] + at0 * wof[2] + at1 * wof[6] + at2 * wof[10] + at3 * wof[14];
  float o3 = bof[3] + at0 * wof[3] + at1 * wof[7] + at2 * wof[11] + at3 * wof[15];
  h_out[((size_t)b << LOG2N) + (rh << 10) + t] =
      make_float4(fmaxf(hn.x + o0, 0.f), fmaxf(hn.y + o1, 0.f),
                  fmaxf(hn.z + o2, 0.f), fmaxf(hn.w + o3, 0.f));
}

__global__ void final_kernel(const float4* __restrict__ h,   // rank-ordered
                             const int* __restrict__ inv,    // node -> global rank
                             const int* __restrict__ src_index, const int* __restrict__ dst_index,
                             const float* __restrict__ timestamp,
                             const float* __restrict__ tw,
                             const float* __restrict__ tb,
                             const float* __restrict__ W_lin,
                             const float* __restrict__ b_lin,
                             float* __restrict__ out) {
  int b = threadIdx.x;
  if (b >= B) return;
  int rs = inv[((size_t)b << LOG2N) + src_index[b]];
  int rd = inv[((size_t)b << LOG2N) + dst_index[b]];
  float4 sx = h[((size_t)b << LOG2N) + rs];
  float4 dx = h[((size_t)b << LOG2N) + rd];
  float ts = timestamp[b];
  float f[12];
  f[0] = sx.x; f[1] = sx.y; f[2] = sx.z; f[3] = sx.w;
  f[4] = dx.x; f[5] = dx.y; f[6] = dx.z; f[7] = dx.w;
#pragma unroll
  for (int j = 0; j < 4; j++) f[8 + j] = __cosf(ts * tw[j] + tb[j]);
#pragma unroll
  for (int c = 0; c < 2; c++) {
    float o = b_lin[c];
#pragma unroll
    for (int j = 0; j < 12; j++) o += f[j] * W_lin[j * 2 + c];
    out[b * 2 + c] = o;
  }
}

}  // namespace

extern "C" void kernel_launch(void* const* d_in, const int* in_sizes, int n_in,
                              void* d_out, int out_size, void* d_ws, size_t ws_size,
                              hipStream_t stream) {
  (void)in_sizes; (void)n_in; (void)out_size; (void)ws_size;
  const float* x         = (const float*)d_in[0];
  const int*   edge_idx  = (const int*)d_in[1];
  const float* edge_time = (const float*)d_in[2];
  const float* timestamp = (const float*)d_in[3];
  const int*   src_index = (const int*)d_in[4];
  const int*   dst_index = (const int*)d_in[5];
  const float* time_w    = (const float*)d_in[6];
  const float* time_b    = (const float*)d_in[7];
  const float* Wq        = (const float*)d_in[8];
  const float* Wk        = (const float*)d_in[9];
  const float* Wv        = (const float*)d_in[10];
  const float* Wo        = (const float*)d_in[11];
  const float* bo        = (const float*)d_in[12];
  const float* W_lin     = (const float*)d_in[13];
  const float* b_lin     = (const float*)d_in[14];

  char* ws = (char*)d_ws;
  float4*   h0  = (float4*)(ws + OFF_H0);
  float4*   h1  = (float4*)(ws + OFF_H1);
  unsigned* ell = (unsigned*)(ws + OFF_ELL);
  unsigned* nr  = (unsigned*)(ws + OFF_NR);
  int*      inv = (int*)(ws + OFF_INV);

  sort_kernel<<<2 * B, 1024, 0, stream>>>(edge_idx, edge_time, timestamp, ell, nr, inv);

  layer_kernel<<<2 * B, 1024, 0, stream>>>((const float4*)x, 0, h1, nr, ell,
                                           time_w, time_b,
                                           Wq + 0 * 16, Wk + 0 * 32, Wv + 0 * 32,
                                           Wo + 0 * 16, bo + 0 * 4);
  layer_kernel<<<2 * B, 1024, 0, stream>>>(h1, 1, h0, nr, ell,
                                           time_w, time_b,
                                           Wq + 1 * 16, Wk + 1 * 32, Wv + 1 * 32,
                                           Wo + 1 * 16, bo + 1 * 4);

  final_kernel<<<1, 128, 0, stream>>>(h0, inv, src_index, dst_index, timestamp,
                                      time_w, time_b, W_lin, b_lin, (float*)d_out);
}

// Round 9
// 195.823 us; speedup vs baseline: 1.0336x; 1.0290x over previous
//
#include <hip/hip_runtime.h>
#include <hip/hip_fp16.h>

namespace {

constexpr int B = 128, N = 2048, E = 32768;
constexpr int LOG2N = 11, LOG2E = 15;
constexpr int QE = 8192;  // edges per quarter block (exact: E/4)

// ws layout (bytes)
constexpr size_t OFF_H0  = 0;                     // B*N float4 = 4 MB
constexpr size_t OFF_H1  = 4u * 1024 * 1024;      // B*N float4 = 4 MB
constexpr size_t OFF_SRT = 8u * 1024 * 1024;      // 512 blocks * QE u32 = 16 MB
constexpr size_t OFF_SEG = 24u * 1024 * 1024;     // 512 blocks * N u32 = 4 MB

// Quarter-batch LDS counting sort (R6 structure — the 185.6us winner), with
// 4B packed records (src | f16(dt)<<16; abs err ~3e-5, validated R7/R8).
// Exactly QE edges per block: no read amplification (R8's dst-range split
// read edges 2x and regressed), no cross-block merge. LDS 44KB -> 2 blocks/CU
// (wave-capped), grid 512 = full chip.
__global__ __launch_bounds__(1024) void sort_kernel(const int* __restrict__ edge_index,
                                                    const float* __restrict__ edge_time,
                                                    const float* __restrict__ timestamp,
                                                    unsigned* __restrict__ sorted,
                                                    unsigned* __restrict__ seg) {
  __shared__ int      cnt[N];        // 8 KB counts -> cursors
  __shared__ int      partial[1024]; // 4 KB
  __shared__ unsigned rec[QE];       // 32 KB packed records
  int blk = blockIdx.x, b = blk >> 2, q = blk & 3, t = threadIdx.x;
  const int* src_arr = edge_index + ((size_t)(2 * b) << LOG2E) + q * QE;
  const int* dst_arr = edge_index + ((size_t)(2 * b + 1) << LOG2E) + q * QE;
  const float* et    = edge_time + ((size_t)b << LOG2E) + q * QE;
  float ts = timestamp[b];

  cnt[t] = 0; cnt[t + 1024] = 0;
  __syncthreads();

  for (int e = t; e < QE; e += 1024) atomicAdd(&cnt[dst_arr[e]], 1);
  __syncthreads();

  // exclusive scan of 2048 counts (2/thread)
  int i0 = 2 * t, i1 = 2 * t + 1;
  int l0 = cnt[i0], l1 = cnt[i1], sum = l0 + l1;
  partial[t] = sum;
  __syncthreads();
  for (int d = 1; d < 1024; d <<= 1) {
    int v = (t >= d) ? partial[t - d] : 0;
    __syncthreads();
    partial[t] += v;
    __syncthreads();
  }
  int run = partial[t] - sum;
  int run2 = run + l0;
  // packed segment descriptor: beg (14b used) | deg<<16
  unsigned* sg = seg + (size_t)blk * N;
  sg[i0] = (unsigned)run  | ((unsigned)l0 << 16);
  sg[i1] = (unsigned)run2 | ((unsigned)l1 << 16);
  cnt[i0] = run;   // cursor
  cnt[i1] = run2;
  __syncthreads();

  // scatter packed (src | f16(dt)<<16) into LDS CSR
  for (int e = t; e < QE; e += 1024) {
    int dst = dst_arr[e], src = src_arr[e];
    float dt = ts - et[e];
    unsigned hd = (unsigned)__half_as_ushort(__float2half(dt));
    int pos = atomicAdd(&cnt[dst], 1);
    rec[pos] = (unsigned)src | (hd << 16);
  }
  __syncthreads();

  // coalesced stream-out: uint4 = 4 records
  const uint4* rec4 = (const uint4*)rec;
  uint4* out4 = (uint4*)(sorted + ((size_t)blk << 13));
#pragma unroll
  for (int i = t; i < QE / 4; i += 1024) out4[i] = rec4[i];
}

// 8 blocks/batch x 256 thr (grid 1024, 32KB LDS -> 4+ blocks/CU, ALL CUs
// busy — every prior layer ran grid 256 = half chip). Thread t owns node
// oct*256+t: walks its 4 quarter-segments with one continuous online softmax.
__global__ __launch_bounds__(256) void layer_kernel(const float4* __restrict__ h_in,
                                                    float4* __restrict__ h_out,
                                                    const unsigned* __restrict__ seg,
                                                    const unsigned* __restrict__ sorted,
                                                    const float* __restrict__ tw,
                                                    const float* __restrict__ tb,
                                                    const float* __restrict__ Wq,
                                                    const float* __restrict__ Wk,
                                                    const float* __restrict__ Wv,
                                                    const float* __restrict__ Wo,
                                                    const float* __restrict__ bo) {
  __shared__ float4 lh[N];  // 32 KB, node-indexed
  int blk = blockIdx.x, b = blk >> 3, oct = blk & 7, t = threadIdx.x;

  const float4* hb = h_in + ((size_t)b << LOG2N);
#pragma unroll
  for (int j = 0; j < 8; j++) {
    int idx = j * 256 + t;
    lh[idx] = hb[idx];
  }

  float twf[4], tbf[4], bof[4], wq[16], wof[16], wk[32], wv[32];
#pragma unroll
  for (int j = 0; j < 4; j++) { twf[j] = tw[j]; tbf[j] = tb[j]; bof[j] = bo[j]; }
#pragma unroll
  for (int j = 0; j < 16; j++) { wq[j] = Wq[j]; wof[j] = Wo[j]; }
#pragma unroll
  for (int j = 0; j < 32; j++) { wk[j] = Wk[j]; wv[j] = Wv[j]; }
  __syncthreads();

  int n = (oct << 8) + t;
  float4 hn = lh[n];
  float q0 = hn.x * wq[0] + hn.y * wq[4] + hn.z * wq[8]  + hn.w * wq[12];
  float q1 = hn.x * wq[1] + hn.y * wq[5] + hn.z * wq[9]  + hn.w * wq[13];
  float q2 = hn.x * wq[2] + hn.y * wq[6] + hn.z * wq[10] + hn.w * wq[14];
  float q3 = hn.x * wq[3] + hn.y * wq[7] + hn.z * wq[11] + hn.w * wq[15];
  const float RS2 = 0.70710678118654752f;
  float u0[8], u1[8];
#pragma unroll
  for (int j = 0; j < 8; j++) {
    u0[j] = RS2 * (q0 * wk[j * 4 + 0] + q1 * wk[j * 4 + 1]);
    u1[j] = RS2 * (q2 * wk[j * 4 + 2] + q3 * wk[j * 4 + 3]);
  }

  float m0 = -INFINITY, m1 = -INFINITY;
  float s0 = 0.f, s1 = 0.f, a00 = 0.f, a01 = 0.f, a10 = 0.f, a11 = 0.f;

#pragma unroll
  for (int q = 0; q < 4; ++q) {
    int qblk = (b << 2) + q;
    unsigned sd = seg[(size_t)qblk * N + n];
    int beg = (int)(sd & 0xFFFFu);
    int deg = (int)(sd >> 16);
    const unsigned* srt = sorted + ((size_t)qblk << 13) + beg;
    unsigned rc = (deg > 0) ? srt[0] : 0u;  // 1-deep prefetch
    for (int j = 0; j < deg; ++j) {
      unsigned rc_next = (j + 1 < deg) ? srt[j + 1] : 0u;
      int src = (int)(rc & 0xFFFFu);
      float dt = __half2float(__ushort_as_half((unsigned short)(rc >> 16)));
      float4 hs = lh[src];
      float p0c = __cosf(dt * twf[0] + tbf[0]);
      float p1c = __cosf(dt * twf[1] + tbf[1]);
      float p2c = __cosf(dt * twf[2] + tbf[2]);
      float p3c = __cosf(dt * twf[3] + tbf[3]);
      float l0 = u0[0] * hs.x + u0[1] * hs.y + u0[2] * hs.z + u0[3] * hs.w
               + u0[4] * p0c + u0[5] * p1c + u0[6] * p2c + u0[7] * p3c;
      float l1 = u1[0] * hs.x + u1[1] * hs.y + u1[2] * hs.z + u1[3] * hs.w
               + u1[4] * p0c + u1[5] * p1c + u1[6] * p2c + u1[7] * p3c;
      float v0 = wv[0] * hs.x + wv[4] * hs.y + wv[8]  * hs.z + wv[12] * hs.w
               + wv[16] * p0c + wv[20] * p1c + wv[24] * p2c + wv[28] * p3c;
      float v1 = wv[1] * hs.x + wv[5] * hs.y + wv[9]  * hs.z + wv[13] * hs.w
               + wv[17] * p0c + wv[21] * p1c + wv[25] * p2c + wv[29] * p3c;
      float v2 = wv[2] * hs.x + wv[6] * hs.y + wv[10] * hs.z + wv[14] * hs.w
               + wv[18] * p0c + wv[22] * p1c + wv[26] * p2c + wv[30] * p3c;
      float v3 = wv[3] * hs.x + wv[7] * hs.y + wv[11] * hs.z + wv[15] * hs.w
               + wv[19] * p0c + wv[23] * p1c + wv[27] * p2c + wv[31] * p3c;
      float nm0 = fmaxf(m0, l0);
      float sc0 = __expf(m0 - nm0);
      float p0  = __expf(l0 - nm0);
      s0 = s0 * sc0 + p0; a00 = a00 * sc0 + p0 * v0; a01 = a01 * sc0 + p0 * v1; m0 = nm0;
      float nm1 = fmaxf(m1, l1);
      float sc1 = __expf(m1 - nm1);
      float p1  = __expf(l1 - nm1);
      s1 = s1 * sc1 + p1; a10 = a10 * sc1 + p1 * v2; a11 = a11 * sc1 + p1 * v3; m1 = nm1;
      rc = rc_next;
    }
  }
  float d0 = (s0 == 0.f) ? 1.f : s0;
  float d1 = (s1 == 0.f) ? 1.f : s1;
  float at0 = a00 / d0, at1 = a01 / d0, at2 = a10 / d1, at3 = a11 / d1;
  float o0 = bof[0] + at0 * wof[0] + at1 * wof[4] + at2 * wof[8]  + at3 * wof[12];
  float o1 = bof[1] + at0 * wof[1] + at1 * wof[5] + at2 * wof[9]  + at3 * wof[13];
  float o2 = bof[2] + at0 * wof[2] + at1 * wof[6] + at2 * wof[10] + at3 * wof[14];
  float o3 = bof[3] + at0 * wof[3] + at1 * wof[7] + at2 * wof[11] + at3 * wof[15];
  h_out[((size_t)b << LOG2N) + n] =
      make_float4(fmaxf(hn.x + o0, 0.f), fmaxf(hn.y + o1, 0.f),
                  fmaxf(hn.z + o2, 0.f), fmaxf(hn.w + o3, 0.f));
}

__global__ void final_kernel(const float4* __restrict__ h,
                             const int* __restrict__ src_index, const int* __restrict__ dst_index,
                             const float* __restrict__ timestamp,
                             const float* __restrict__ tw,
                             const float* __restrict__ tb,
                             const float* __restrict__ W_lin,
                             const float* __restrict__ b_lin,
                             float* __restrict__ out) {
  int b = threadIdx.x;
  if (b >= B) return;
  float4 sx = h[(((size_t)b) << LOG2N) + src_index[b]];
  float4 dx = h[(((size_t)b) << LOG2N) + dst_index[b]];
  float ts = timestamp[b];
  float f[12];
  f[0] = sx.x; f[1] = sx.y; f[2] = sx.z; f[3] = sx.w;
  f[4] = dx.x; f[5] = dx.y; f[6] = dx.z; f[7] = dx.w;
#pragma unroll
  for (int j = 0; j < 4; j++) f[8 + j] = __cosf(ts * tw[j] + tb[j]);
#pragma unroll
  for (int c = 0; c < 2; c++) {
    float o = b_lin[c];
#pragma unroll
    for (int j = 0; j < 12; j++) o += f[j] * W_lin[j * 2 + c];
    out[b * 2 + c] = o;
  }
}

}  // namespace

extern "C" void kernel_launch(void* const* d_in, const int* in_sizes, int n_in,
                              void* d_out, int out_size, void* d_ws, size_t ws_size,
                              hipStream_t stream) {
  (void)in_sizes; (void)n_in; (void)out_size; (void)ws_size;
  const float* x         = (const float*)d_in[0];
  const int*   edge_idx  = (const int*)d_in[1];
  const float* edge_time = (const float*)d_in[2];
  const float* timestamp = (const float*)d_in[3];
  const int*   src_index = (const int*)d_in[4];
  const int*   dst_index = (const int*)d_in[5];
  const float* time_w    = (const float*)d_in[6];
  const float* time_b    = (const float*)d_in[7];
  const float* Wq        = (const float*)d_in[8];
  const float* Wk        = (const float*)d_in[9];
  const float* Wv        = (const float*)d_in[10];
  const float* Wo        = (const float*)d_in[11];
  const float* bo        = (const float*)d_in[12];
  const float* W_lin     = (const float*)d_in[13];
  const float* b_lin     = (const float*)d_in[14];

  char* ws = (char*)d_ws;
  float4*   h0     = (float4*)(ws + OFF_H0);
  float4*   h1     = (float4*)(ws + OFF_H1);
  unsigned* sorted = (unsigned*)(ws + OFF_SRT);
  unsigned* seg    = (unsigned*)(ws + OFF_SEG);

  sort_kernel<<<4 * B, 1024, 0, stream>>>(edge_idx, edge_time, timestamp, sorted, seg);

  layer_kernel<<<8 * B, 256, 0, stream>>>((const float4*)x, h1, seg, sorted,
                                          time_w, time_b,
                                          Wq + 0 * 16, Wk + 0 * 32, Wv + 0 * 32,
                                          Wo + 0 * 16, bo + 0 * 4);
  layer_kernel<<<8 * B, 256, 0, stream>>>(h1, h0, seg, sorted,
                                          time_w, time_b,
                                          Wq + 1 * 16, Wk + 1 * 32, Wv + 1 * 32,
                                          Wo + 1 * 16, bo + 1 * 4);

  final_kernel<<<1, 128, 0, stream>>>(h0, src_index, dst_index, timestamp, time_w, time_b,
                                      W_lin, b_lin, (float*)d_out);
}